// Round 6
// baseline (17.186 us; speedup 1.0000x reference)
//
#include <hip/hip_runtime.h>
#include <math.h>

// Problem constants (from reference)
#define Bn 256
#define Ln 2048
#define EPSd 1e-4
#define DIAG_MIN 0.1
#define W2PAD 17  // pad w_me2 rows (16 -> 17 f32) to spread LDS banks

__device__ __forceinline__ double silu_d(double x) { return x / (1.0 + exp(-x)); }
__device__ __forceinline__ double softplus_d(double x) {
    return fmax(x, 0.0) + log1p(exp(-fabs(x)));
}

// tril row-major (i,j) for m = 0..35 — R3-proven declaration form.
__device__ const signed char ROW36[36] = {0,1,1,2,2,2,3,3,3,3,4,4,4,4,4,5,5,5,5,5,5,6,6,6,6,6,6,6,7,7,7,7,7,7,7,7};
__device__ const signed char COL36[36] = {0,0,1,0,1,2,0,1,2,3,0,1,2,3,4,0,1,2,3,4,5,0,1,2,3,4,5,6,0,1,2,3,4,5,6,7};
#define DIAG_MASK ((1ull<<0)|(1ull<<2)|(1ull<<5)|(1ull<<9)|(1ull<<14)|(1ull<<20)|(1ull<<27)|(1ull<<35))

// One block per batch row, 256 threads (4 waves). 3 barriers total.
// NOTE: NO __shfl anywhere — R4/R5 failed from __shfl reading inactive source
// lanes inside divergent branches (ds_bpermute returns 0 for inactive lanes).
__global__ __launch_bounds__(256) void memodel_kernel(
    const float* __restrict__ values,
    const float* __restrict__ se_in_w, const float* __restrict__ se_in_b,
    const float* __restrict__ se_conv_w, const float* __restrict__ se_conv_b,
    const float* __restrict__ se_out_w, const float* __restrict__ se_out_b,
    const float* __restrict__ me_w1, const float* __restrict__ me_b1,
    const float* __restrict__ me_w2, const float* __restrict__ me_b2,
    const float* __restrict__ ef_w1, const float* __restrict__ ef_b1,
    const float* __restrict__ ef_w2, const float* __restrict__ ef_b2,
    const float* __restrict__ ef_scale,
    const float* __restrict__ mu_w1, const float* __restrict__ mu_b1,
    const float* __restrict__ mu_w2, const float* __restrict__ mu_b2,
    float* __restrict__ out)
{
    const int b = blockIdx.x;
    const int tid = threadIdx.x;
    const int lane = tid & 63;
    const int wav = tid >> 6;

    // Weights cached in LDS as f32 (f32->f64 conversion exact; numerics identical)
    __shared__ float w_me1f[128], b_me1f[16], w_me2f[36 * W2PAD], b_me2f[36];
    __shared__ float cvwf[384], cvbf[8], sowf[64], sobf[8];
    __shared__ float ef_w1f[256], ef_b1f[16], ef_w2f[128], ef_b2f[8], ef_sc_f[1];
    __shared__ float mu_w1f[64], mu_b1f[8], mu_w2f[8], mu_b2f[1];
    __shared__ double h16[4][16];    // in-proj at t = L-4..L-1
    __shared__ double sh[2][8];      // silu(conv) at t = L-2, L-1
    __shared__ double zl[2][8];      // z at t = L-2, L-1
    __shared__ double h1s[17][16];   // metric-net hidden, e = 0..16
    __shared__ double Lrs[17][36];   // tril factors (softplus'd diag)
    __shared__ double gs[17][36];    // g = L L^T (sym storage), e = 1..16
    __shared__ double Apart[8][8], Bpart[8], invdiag[8], solveV[8];
    __shared__ double ageo_s[8], h2s[16], d2z_s[8], h3s[8];

    double vL1 = 0.0, vL2 = 0.0;

    if (wav == 0) {
        // Phase 1a (wave 0, 64 lanes): h16[t][c] = se_in_w[c]*v_t + se_in_b[c]
        const int t = lane >> 4, c = lane & 15;
        double v = (double)values[(size_t)b * Ln + (Ln - 4 + t)];
        vL1 = (double)values[(size_t)b * Ln + (Ln - 1)];
        vL2 = (double)values[(size_t)b * Ln + (Ln - 2)];
        h16[t][c] = (double)se_in_w[c] * v + (double)se_in_b[c];
    } else {
        // Waves 1-3: prefetch ALL weights into LDS (overlaps wave 0's phase 1a)
        const int i0 = tid - 64;  // 0..191
        for (int i = i0; i < 128; i += 192) w_me1f[i] = me_w1[i];
        for (int i = i0; i < 16;  i += 192) b_me1f[i] = me_b1[i];
        for (int i = i0; i < 576; i += 192) w_me2f[(i >> 4) * W2PAD + (i & 15)] = me_w2[i];
        for (int i = i0; i < 36;  i += 192) b_me2f[i] = me_b2[i];
        for (int i = i0; i < 384; i += 192) cvwf[i] = se_conv_w[i];
        for (int i = i0; i < 8;   i += 192) cvbf[i] = se_conv_b[i];
        for (int i = i0; i < 64;  i += 192) sowf[i] = se_out_w[i];
        for (int i = i0; i < 8;   i += 192) sobf[i] = se_out_b[i];
        for (int i = i0; i < 256; i += 192) ef_w1f[i] = ef_w1[i];
        for (int i = i0; i < 16;  i += 192) ef_b1f[i] = ef_b1[i];
        for (int i = i0; i < 128; i += 192) ef_w2f[i] = ef_w2[i];
        for (int i = i0; i < 8;   i += 192) ef_b2f[i] = ef_b2[i];
        for (int i = i0; i < 64;  i += 192) mu_w1f[i] = mu_w1[i];
        for (int i = i0; i < 8;   i += 192) mu_b1f[i] = mu_b1[i];
        for (int i = i0; i < 8;   i += 192) mu_w2f[i] = mu_w2[i];
        if (i0 == 0) { ef_sc_f[0] = ef_scale[0]; mu_b2f[0] = mu_b2[0]; }
    }
    __syncthreads();  // ===== B1: h16 + all weights visible =====

    // Phase 1b+1c (wave 0, lanes 0-15): conv+silu then out-proj -> zl.
    // sh write->read is same-wave LDS (in-order DS pipe); R3-identical math.
    if (wav == 0 && lane < 16) {
        const int tq = lane >> 3, d = lane & 7;
        {
            double s = (double)cvbf[d];
            #pragma unroll
            for (int k = 0; k < 3; ++k)
                #pragma unroll
                for (int c = 0; c < 16; ++c)
                    s += (double)cvwf[d * 48 + c * 3 + k] * h16[tq + k][c];
            sh[tq][d] = silu_d(s);
        }
        {
            double s = (double)sobf[d];
            #pragma unroll
            for (int c = 0; c < 8; ++c) s += (double)sowf[d * 8 + c] * sh[tq][c];
            zl[tq][d] = s;
        }
    }
    __syncthreads();  // ===== B2: zl visible to all waves =====

    // Phase 2: each wave owns 4 evals end-to-end (wave-internal, no barriers).
    {
        const int ebase = 1 + wav * 4;  // e = ebase..ebase+3 (1..16 across waves)
        double z1[8];
        #pragma unroll
        for (int i = 0; i < 8; ++i) z1[i] = zl[1][i];

        // h1 = silu(me_w1 zz + b1): lane = q*16 + j, e = ebase+q; eps folded inline.
        {
            const int q = lane >> 4, j = lane & 15;
            const int e = ebase + q;
            const double sgn = (e <= 8) ? EPSd : -EPSd;
            const int pid = (e - 1) & 7;
            double s = (double)b_me1f[j];
            #pragma unroll
            for (int i = 0; i < 8; ++i) {
                double zi = z1[i] + ((i == pid) ? sgn : 0.0);
                s += (double)w_me1f[j * 8 + i] * zi;
            }
            h1s[e][j] = silu_d(s);
        }
        // wave 3 extra: base eval (e=0) h1
        if (wav == 3 && lane < 16) {
            const int j = lane;
            double s = (double)b_me1f[j];
            #pragma unroll
            for (int i = 0; i < 8; ++i) s += (double)w_me1f[j * 8 + i] * z1[i];
            h1s[0][j] = silu_d(s);
        }

        // Lr = me_w2 h1 + b2 (+softplus diag): 144 tasks/wave.
        #pragma unroll
        for (int r = 0; r < 3; ++r) {
            const int idx = lane + r * 64;
            if (idx < 144) {
                const int q = idx / 36, m = idx - q * 36;
                const int e = ebase + q;
                double s = (double)b_me2f[m];
                const float* w = &w_me2f[m * W2PAD];
                const double* h = &h1s[e][0];
                #pragma unroll
                for (int j = 0; j < 16; ++j) s += (double)w[j] * h[j];
                if ((DIAG_MASK >> m) & 1ull) s = softplus_d(s) + DIAG_MIN;
                Lrs[e][m] = s;
            }
        }
        // wave 3 extra: base eval Lr (needed by the solve)
        if (wav == 3 && lane < 36) {
            const int m = lane;
            double s = (double)b_me2f[m];
            const float* w = &w_me2f[m * W2PAD];
            const double* h = &h1s[0][0];
            #pragma unroll
            for (int j = 0; j < 16; ++j) s += (double)w[j] * h[j];
            if ((DIAG_MASK >> m) & 1ull) s = softplus_d(s) + DIAG_MIN;
            Lrs[0][m] = s;
        }

        // g = L L^T for own evals: 144 tasks/wave.
        #pragma unroll
        for (int r = 0; r < 3; ++r) {
            const int idx = lane + r * 64;
            if (idx < 144) {
                const int q = idx / 36, m = idx - q * 36;
                const int e = ebase + q;
                const int i = ROW36[m], j = COL36[m];
                const double* Li = &Lrs[e][i * (i + 1) / 2];
                const double* Lj = &Lrs[e][j * (j + 1) / 2];
                double s = 0.0;
                for (int k = 0; k <= j; ++k) s += Li[k] * Lj[k];
                gs[e][m] = s;
            }
        }
    }
    __syncthreads();  // ===== B3: all gs / Lrs[0] visible =====
    if (wav != 0) return;  // tail is wave 0 only, barrier-free

    // Phase 3: FD contraction (lanes 0-7) + diag reciprocals (lanes 8-15).
    if (lane >= 8 && lane < 16) {
        const int i = lane - 8;
        invdiag[i] = 1.0 / Lrs[0][i * (i + 1) / 2 + i];
    }
    if (lane < 8) {
        const int r = lane;
        double dz[8];
        #pragma unroll
        for (int i = 0; i < 8; ++i) dz[i] = zl[1][i] - zl[0][i];
        double w[8];
        #pragma unroll
        for (int l = 0; l < 8; ++l) w[l] = 0.0;
        const double inv2e = 1.0 / (2.0 * EPSd);
        #pragma unroll
        for (int m = 0; m < 36; ++m) {
            const int i = ROW36[m], j = COL36[m];  // folds to immediates (unrolled)
            double d = (gs[1 + r][m] - gs[9 + r][m]) * inv2e;
            w[j] += d * dz[i];
            if (i != j) w[i] += d * dz[j];
        }
        double Br = 0.0;
        #pragma unroll
        for (int l = 0; l < 8; ++l) {
            Apart[r][l] = dz[r] * w[l];
            Br += w[l] * dz[l];
        }
        Bpart[r] = Br;
    }

    // Phase 4a: v[l] = 2*sum_r A[r][l] - B[l]  (lanes 0-7, same-wave LDS).
    if (lane < 8) {
        double a = 0.0;
        #pragma unroll
        for (int r = 0; r < 8; ++r) a += Apart[r][lane];
        solveV[lane] = 2.0 * a - Bpart[lane];
    }

    // Phase 4b: solve g x = v via Cholesky factor (lane 0, fully unrolled).
    if (lane == 0) {
        double y[8];
        #pragma unroll
        for (int i = 0; i < 8; ++i) {
            double s = solveV[i];
            #pragma unroll
            for (int j = 0; j < 8; ++j) if (j < i) s -= Lrs[0][i * (i + 1) / 2 + j] * y[j];
            y[i] = s * invdiag[i];
        }
        double x[8];
        #pragma unroll
        for (int i = 7; i >= 0; --i) {
            double s = y[i];
            #pragma unroll
            for (int j = 0; j < 8; ++j) if (j > i) s -= Lrs[0][j * (j + 1) / 2 + i] * x[j];
            x[i] = s * invdiag[i];
            ageo_s[i] = -0.5 * x[i];
        }
    }

    // Phase 4c: ef head layer 1 (lanes 0-15): h2 = tanh(ef_w1 [z,dz] + b1).
    if (lane < 16) {
        double s = (double)ef_b1f[lane];
        const float* w = &ef_w1f[lane * 16];
        #pragma unroll
        for (int i = 0; i < 8; ++i) s += (double)w[i] * zl[1][i];
        #pragma unroll
        for (int i = 0; i < 8; ++i) s += (double)w[8 + i] * (zl[1][i] - zl[0][i]);
        h2s[lane] = tanh(s);
    }

    // Phase 4d: d2z = a_geo + ef_scale * (ef_w2 h2 + b2)  (lanes 0-7).
    if (lane < 8) {
        double s = (double)ef_b2f[lane];
        const float* w = &ef_w2f[lane * 16];
        #pragma unroll
        for (int j = 0; j < 16; ++j) s += (double)w[j] * h2s[j];
        d2z_s[lane] = ageo_s[lane] + s * (double)ef_sc_f[0];
    }

    // Phase 4e: mu head layer 1 (lanes 0-7): h3 = silu(mu_w1 d2z + b1).
    if (lane < 8) {
        double s = (double)mu_b1f[lane];
        const float* w = &mu_w1f[lane * 8];
        #pragma unroll
        for (int i = 0; i < 8; ++i) s += (double)w[i] * d2z_s[i];
        h3s[lane] = silu_d(s);
    }

    // Phase 4f: final dot + output (lane 0; vL1/vL2 in registers since phase 1).
    if (lane == 0) {
        double mu = (double)mu_b2f[0];
        #pragma unroll
        for (int j = 0; j < 8; ++j) mu += (double)mu_w2f[j] * h3s[j];
        out[b] = (float)(vL1 + (vL1 - vL2) + mu);
    }
}

extern "C" void kernel_launch(void* const* d_in, const int* in_sizes, int n_in,
                              void* d_out, int out_size, void* d_ws, size_t ws_size,
                              hipStream_t stream) {
    (void)in_sizes; (void)n_in; (void)out_size; (void)d_ws; (void)ws_size;
    const float* values    = (const float*)d_in[0];
    const float* se_in_w   = (const float*)d_in[1];
    const float* se_in_b   = (const float*)d_in[2];
    const float* se_conv_w = (const float*)d_in[3];
    const float* se_conv_b = (const float*)d_in[4];
    const float* se_out_w  = (const float*)d_in[5];
    const float* se_out_b  = (const float*)d_in[6];
    const float* me_w1     = (const float*)d_in[7];
    const float* me_b1     = (const float*)d_in[8];
    const float* me_w2     = (const float*)d_in[9];
    const float* me_b2     = (const float*)d_in[10];
    const float* ef_w1     = (const float*)d_in[11];
    const float* ef_b1     = (const float*)d_in[12];
    const float* ef_w2     = (const float*)d_in[13];
    const float* ef_b2     = (const float*)d_in[14];
    const float* ef_scale  = (const float*)d_in[15];
    const float* mu_w1     = (const float*)d_in[16];
    const float* mu_b1     = (const float*)d_in[17];
    const float* mu_w2     = (const float*)d_in[18];
    const float* mu_b2     = (const float*)d_in[19];
    float* out = (float*)d_out;

    hipLaunchKernelGGL(memodel_kernel, dim3(Bn), dim3(256), 0, stream,
                       values, se_in_w, se_in_b, se_conv_w, se_conv_b,
                       se_out_w, se_out_b, me_w1, me_b1, me_w2, me_b2,
                       ef_w1, ef_b1, ef_w2, ef_b2, ef_scale,
                       mu_w1, mu_b1, mu_w2, mu_b2, out);
}

// Round 7
// 16.793 us; speedup vs baseline: 1.0234x; 1.0234x over previous
//
#include <hip/hip_runtime.h>
#include <math.h>

// Problem constants (from reference)
#define Bn 256
#define Ln 2048
#define EPSd 1e-4
#define DIAG_MIN 0.1
#define W2PAD 17  // pad w_me2 rows (16 -> 17 f32) to spread LDS banks

__device__ __forceinline__ double silu_d(double x) { return x / (1.0 + exp(-x)); }
__device__ __forceinline__ double softplus_d(double x) {
    return fmax(x, 0.0) + log1p(exp(-fabs(x)));
}

// tril row-major (i,j) for m = 0..35 — R3-proven declaration form.
// NO __shfl anywhere (R4/R5 lesson: inactive-source-lane reads return garbage).
__device__ const signed char ROW36[36] = {0,1,1,2,2,2,3,3,3,3,4,4,4,4,4,5,5,5,5,5,5,6,6,6,6,6,6,6,7,7,7,7,7,7,7,7};
__device__ const signed char COL36[36] = {0,0,1,0,1,2,0,1,2,3,0,1,2,3,4,0,1,2,3,4,5,0,1,2,3,4,5,6,0,1,2,3,4,5,6,7};
#define DIAG_MASK ((1ull<<0)|(1ull<<2)|(1ull<<5)|(1ull<<9)|(1ull<<14)|(1ull<<20)|(1ull<<27)|(1ull<<35))

// One block per batch row, 256 threads (4 waves). R3 skeleton (13 barriers,
// flat strided work distribution) + full weight prefetch + scratch-free tail.
__global__ __launch_bounds__(256) void memodel_kernel(
    const float* __restrict__ values,
    const float* __restrict__ se_in_w, const float* __restrict__ se_in_b,
    const float* __restrict__ se_conv_w, const float* __restrict__ se_conv_b,
    const float* __restrict__ se_out_w, const float* __restrict__ se_out_b,
    const float* __restrict__ me_w1, const float* __restrict__ me_b1,
    const float* __restrict__ me_w2, const float* __restrict__ me_b2,
    const float* __restrict__ ef_w1, const float* __restrict__ ef_b1,
    const float* __restrict__ ef_w2, const float* __restrict__ ef_b2,
    const float* __restrict__ ef_scale,
    const float* __restrict__ mu_w1, const float* __restrict__ mu_b1,
    const float* __restrict__ mu_w2, const float* __restrict__ mu_b2,
    float* __restrict__ out)
{
    const int b = blockIdx.x;
    const int tid = threadIdx.x;

    // All weights cached in LDS as f32 (f32->f64 widening is exact).
    __shared__ float w_me1f[128], b_me1f[16], w_me2f[36 * W2PAD], b_me2f[36];
    __shared__ float cvwf[384], cvbf[8], sowf[64], sobf[8];
    __shared__ float ef_w1f[256], ef_b1f[16], ef_w2f[128], ef_b2f[8], ef_sc_f[1];
    __shared__ float mu_w1f[64], mu_b1f[8], mu_w2f[8], mu_b2f[1];
    __shared__ double h16[4][16];    // in-proj at t = L-4..L-1
    __shared__ double sh[2][8];      // silu(conv) at t = L-2, L-1
    __shared__ double zl[2][8];      // z at t = L-2, L-1
    __shared__ double vls[2];        // values at L-1, L-2
    __shared__ double zs[17][8];     // 17 metric-eval points
    __shared__ double h1s[17][16];   // metric-net hidden
    __shared__ double Lrs[17][36];   // tril factors (softplus'd diag)
    __shared__ double gs[17][36];    // g = L L^T (sym storage), e = 1..16
    __shared__ double Apart[8][8], Bpart[8], invdiag[8], solveV[8];
    __shared__ double ageo_s[8], h2s[16], d2z_s[8], h3s[8];

    // ---- Weight prefetch: ALL arrays, all 256 threads, before first barrier ----
    for (int i = tid; i < 128; i += 256) w_me1f[i] = me_w1[i];
    for (int i = tid; i < 16;  i += 256) b_me1f[i] = me_b1[i];
    for (int i = tid; i < 576; i += 256) w_me2f[(i >> 4) * W2PAD + (i & 15)] = me_w2[i];
    for (int i = tid; i < 36;  i += 256) b_me2f[i] = me_b2[i];
    for (int i = tid; i < 384; i += 256) cvwf[i] = se_conv_w[i];
    for (int i = tid; i < 8;   i += 256) cvbf[i] = se_conv_b[i];
    for (int i = tid; i < 64;  i += 256) sowf[i] = se_out_w[i];
    for (int i = tid; i < 8;   i += 256) sobf[i] = se_out_b[i];
    for (int i = tid; i < 256; i += 256) ef_w1f[i] = ef_w1[i];
    for (int i = tid; i < 16;  i += 256) ef_b1f[i] = ef_b1[i];
    for (int i = tid; i < 128; i += 256) ef_w2f[i] = ef_w2[i];
    for (int i = tid; i < 8;   i += 256) ef_b2f[i] = ef_b2[i];
    for (int i = tid; i < 64;  i += 256) mu_w1f[i] = mu_w1[i];
    for (int i = tid; i < 8;   i += 256) mu_b1f[i] = mu_b1[i];
    for (int i = tid; i < 8;   i += 256) mu_w2f[i] = mu_w2[i];
    if (tid == 0) { ef_sc_f[0] = ef_scale[0]; mu_b2f[0] = mu_b2[0]; }

    // Phase 1a: h = v * se_in_w + se_in_b at the 4 trailing steps (64 lanes).
    if (tid < 64) {
        int t = tid >> 4, c = tid & 15;
        double v = (double)values[(size_t)b * Ln + (Ln - 4 + t)];
        h16[t][c] = (double)se_in_w[c] * v + (double)se_in_b[c];
        if (tid < 2) vls[tid] = (double)values[(size_t)b * Ln + (Ln - 1 - tid)];
    }
    __syncthreads();

    // Phase 1b: causal conv (k=3, left-pad 2) + silu at t = L-2, L-1 (16 lanes).
    if (tid < 16) {
        int t = tid >> 3, d = tid & 7;
        double s = (double)cvbf[d];
        for (int k = 0; k < 3; ++k)
            for (int c = 0; c < 16; ++c)
                s += (double)cvwf[d * 48 + c * 3 + k] * h16[t + k][c];
        sh[t][d] = silu_d(s);
    }
    __syncthreads();

    // Phase 1c: out-projection -> z (16 lanes).
    if (tid < 16) {
        int t = tid >> 3, d = tid & 7;
        double s = (double)sobf[d];
        for (int c = 0; c < 8; ++c) s += (double)sowf[d * 8 + c] * sh[t][c];
        zl[t][d] = s;
    }
    __syncthreads();

    // Phase 2a: build the 17 eval points (e=0 base; 1..8 +eps; 9..16 -eps).
    if (tid < 136) {
        int e = tid >> 3, i = tid & 7;
        double v = zl[1][i];
        if (e >= 1 && e <= 8)  { if (i == e - 1) v += EPSd; }
        else if (e >= 9)       { if (i == e - 9) v -= EPSd; }
        zs[e][i] = v;
    }
    __syncthreads();

    // Phase 2b: h1 = silu(me_w1 zz + b1): 272 dot-8s over 256 lanes.
    for (int idx = tid; idx < 272; idx += 256) {
        int e = idx >> 4, j = idx & 15;
        double s = (double)b_me1f[j];
        const float* w = &w_me1f[j * 8];
        const double* z = &zs[e][0];
        for (int i = 0; i < 8; ++i) s += (double)w[i] * z[i];
        h1s[e][j] = silu_d(s);
    }
    __syncthreads();

    // Phase 2c: Lr = me_w2 h1 + b2 (+softplus on diag): 612 dot-16s over 256 lanes.
    for (int idx = tid; idx < 612; idx += 256) {
        int e = idx / 36, m = idx - e * 36;
        double s = (double)b_me2f[m];
        const float* w = &w_me2f[m * W2PAD];
        const double* h = &h1s[e][0];
        for (int j = 0; j < 16; ++j) s += (double)w[j] * h[j];
        if ((DIAG_MASK >> m) & 1ull) s = softplus_d(s) + DIAG_MIN;
        Lrs[e][m] = s;
    }
    __syncthreads();

    // Phase 2d: g = L L^T for e = 1..16: 576 short dots over 256 lanes.
    for (int idx = tid; idx < 576; idx += 256) {
        int e = 1 + idx / 36, m = idx - (e - 1) * 36;
        int i = ROW36[m], j = COL36[m];
        const double* Li = &Lrs[e][i * (i + 1) / 2];
        const double* Lj = &Lrs[e][j * (j + 1) / 2];
        double s = 0.0;
        for (int k = 0; k <= j; ++k) s += Li[k] * Lj[k];
        gs[e][m] = s;
    }
    __syncthreads();

    // Phase 3: FD contraction (lanes 0-7, static-index -> no scratch)
    //          + diag reciprocals (lanes 8-15).
    if (tid >= 8 && tid < 16) {
        const int i = tid - 8;
        invdiag[i] = 1.0 / Lrs[0][i * (i + 1) / 2 + i];
    }
    if (tid < 8) {
        const int r = tid;
        double dz[8];
        #pragma unroll
        for (int i = 0; i < 8; ++i) dz[i] = zl[1][i] - zl[0][i];
        double w[8];
        #pragma unroll
        for (int l = 0; l < 8; ++l) w[l] = 0.0;
        const double inv2e = 1.0 / (2.0 * EPSd);
        #pragma unroll
        for (int m = 0; m < 36; ++m) {
            const int i = ROW36[m], j = COL36[m];  // folds to immediates (unrolled)
            double d = (gs[1 + r][m] - gs[9 + r][m]) * inv2e;
            w[j] += d * dz[i];
            if (i != j) w[i] += d * dz[j];
        }
        double Br = 0.0;
        #pragma unroll
        for (int l = 0; l < 8; ++l) {
            Apart[r][l] = dz[r] * w[l];
            Br += w[l] * dz[l];
        }
        Bpart[r] = Br;
    }
    __syncthreads();

    // Phase 4a: v[l] = 2*sum_r A[r][l] - B[l]  (8 lanes).
    if (tid < 8) {
        double a = 0.0;
        #pragma unroll
        for (int r = 0; r < 8; ++r) a += Apart[r][tid];
        solveV[tid] = 2.0 * a - Bpart[tid];
    }
    __syncthreads();

    // Phase 4b: solve g x = v via Cholesky factor (lane 0, fully unrolled).
    if (tid == 0) {
        double y[8];
        #pragma unroll
        for (int i = 0; i < 8; ++i) {
            double s = solveV[i];
            #pragma unroll
            for (int j = 0; j < 8; ++j) if (j < i) s -= Lrs[0][i * (i + 1) / 2 + j] * y[j];
            y[i] = s * invdiag[i];
        }
        double x[8];
        #pragma unroll
        for (int i = 7; i >= 0; --i) {
            double s = y[i];
            #pragma unroll
            for (int j = 0; j < 8; ++j) if (j > i) s -= Lrs[0][j * (j + 1) / 2 + i] * x[j];
            x[i] = s * invdiag[i];
            ageo_s[i] = -0.5 * x[i];
        }
    }
    __syncthreads();

    // Phase 4c: ef head layer 1 (16 lanes): h2 = tanh(ef_w1 [z,dz] + b1).
    if (tid < 16) {
        double s = (double)ef_b1f[tid];
        const float* w = &ef_w1f[tid * 16];
        for (int i = 0; i < 8; ++i)  s += (double)w[i] * zl[1][i];
        for (int i = 0; i < 8; ++i)  s += (double)w[8 + i] * (zl[1][i] - zl[0][i]);
        h2s[tid] = tanh(s);
    }
    __syncthreads();

    // Phase 4d: d2z = a_geo + ef_scale * (ef_w2 h2 + b2)  (8 lanes).
    if (tid < 8) {
        double s = (double)ef_b2f[tid];
        const float* w = &ef_w2f[tid * 16];
        for (int j = 0; j < 16; ++j) s += (double)w[j] * h2s[j];
        d2z_s[tid] = ageo_s[tid] + s * (double)ef_sc_f[0];
    }
    __syncthreads();

    // Phase 4e: mu head layer 1 (8 lanes): h3 = silu(mu_w1 d2z + b1).
    if (tid < 8) {
        double s = (double)mu_b1f[tid];
        const float* w = &mu_w1f[tid * 8];
        for (int i = 0; i < 8; ++i) s += (double)w[i] * d2z_s[i];
        h3s[tid] = silu_d(s);
    }
    __syncthreads();

    // Phase 4f: final dot + output (lane 0; vL1/vL2 staged in LDS at phase 1a).
    if (tid == 0) {
        double mu = (double)mu_b2f[0];
        for (int j = 0; j < 8; ++j) mu += (double)mu_w2f[j] * h3s[j];
        double vL1 = vls[0], vL2 = vls[1];
        out[b] = (float)(vL1 + (vL1 - vL2) + mu);
    }
}

extern "C" void kernel_launch(void* const* d_in, const int* in_sizes, int n_in,
                              void* d_out, int out_size, void* d_ws, size_t ws_size,
                              hipStream_t stream) {
    (void)in_sizes; (void)n_in; (void)out_size; (void)d_ws; (void)ws_size;
    const float* values    = (const float*)d_in[0];
    const float* se_in_w   = (const float*)d_in[1];
    const float* se_in_b   = (const float*)d_in[2];
    const float* se_conv_w = (const float*)d_in[3];
    const float* se_conv_b = (const float*)d_in[4];
    const float* se_out_w  = (const float*)d_in[5];
    const float* se_out_b  = (const float*)d_in[6];
    const float* me_w1     = (const float*)d_in[7];
    const float* me_b1     = (const float*)d_in[8];
    const float* me_w2     = (const float*)d_in[9];
    const float* me_b2     = (const float*)d_in[10];
    const float* ef_w1     = (const float*)d_in[11];
    const float* ef_b1     = (const float*)d_in[12];
    const float* ef_w2     = (const float*)d_in[13];
    const float* ef_b2     = (const float*)d_in[14];
    const float* ef_scale  = (const float*)d_in[15];
    const float* mu_w1     = (const float*)d_in[16];
    const float* mu_b1     = (const float*)d_in[17];
    const float* mu_w2     = (const float*)d_in[18];
    const float* mu_b2     = (const float*)d_in[19];
    float* out = (float*)d_out;

    hipLaunchKernelGGL(memodel_kernel, dim3(Bn), dim3(256), 0, stream,
                       values, se_in_w, se_in_b, se_conv_w, se_conv_b,
                       se_out_w, se_out_b, me_w1, me_b1, me_w2, me_b2,
                       ef_w1, ef_b1, ef_w2, ef_b2, ef_scale,
                       mu_w1, mu_b1, mu_w2, mu_b2, out);
}

// Round 8
// 15.858 us; speedup vs baseline: 1.0837x; 1.0589x over previous
//
#include <hip/hip_runtime.h>
#include <math.h>

// Problem constants (from reference)
#define Bn 256
#define Ln 2048
#define EPSd 1e-4
#define DIAG_MIN 0.1

#define W2PAD 17  // pad w_me2 rows (16 -> 17 doubles) to break LDS bank aliasing

__device__ __forceinline__ double silu_d(double x) { return x / (1.0 + exp(-x)); }
__device__ __forceinline__ double softplus_d(double x) {
    return fmax(x, 0.0) + log1p(exp(-fabs(x)));
}

// tril row-major (i,j) for m = 0..35
__device__ const signed char ROW36[36] = {0,1,1,2,2,2,3,3,3,3,4,4,4,4,4,5,5,5,5,5,5,6,6,6,6,6,6,6,7,7,7,7,7,7,7,7};
__device__ const signed char COL36[36] = {0,0,1,0,1,2,0,1,2,3,0,1,2,3,4,0,1,2,3,4,5,0,1,2,3,4,5,6,0,1,2,3,4,5,6,7};
// diagonal m positions: 0,2,5,9,14,20,27,35
#define DIAG_MASK ((1ull<<0)|(1ull<<2)|(1ull<<5)|(1ull<<9)|(1ull<<14)|(1ull<<20)|(1ull<<27)|(1ull<<35))

// One block per batch row, 256 threads (4 waves). R3-champion structure;
// only phase 3 and phase 4b changed to scratch-free forms.
__global__ __launch_bounds__(256) void memodel_kernel(
    const float* __restrict__ values,
    const float* __restrict__ se_in_w, const float* __restrict__ se_in_b,
    const float* __restrict__ se_conv_w, const float* __restrict__ se_conv_b,
    const float* __restrict__ se_out_w, const float* __restrict__ se_out_b,
    const float* __restrict__ me_w1, const float* __restrict__ me_b1,
    const float* __restrict__ me_w2, const float* __restrict__ me_b2,
    const float* __restrict__ ef_w1, const float* __restrict__ ef_b1,
    const float* __restrict__ ef_w2, const float* __restrict__ ef_b2,
    const float* __restrict__ ef_scale,
    const float* __restrict__ mu_w1, const float* __restrict__ mu_b1,
    const float* __restrict__ mu_w2, const float* __restrict__ mu_b2,
    float* __restrict__ out)
{
    const int b = blockIdx.x;
    const int tid = threadIdx.x;

    __shared__ double w_me1[16 * 8], b_me1[16], w_me2[36 * W2PAD], b_me2[36];
    __shared__ double h16[4][16];    // in-proj at t = L-4..L-1
    __shared__ double sh[2][8];      // silu(conv) at t = L-2, L-1
    __shared__ double zl[2][8];      // z at t = L-2, L-1
    __shared__ double zs[17][8];     // 17 metric-eval points
    __shared__ double h1s[17][16];   // hidden activations
    __shared__ double Lrs[17][36];   // tril factors (softplus'd diag)
    __shared__ double gs[17][36];    // g = L L^T (sym storage), slots 1..16
    __shared__ double Apart[8][8];
    __shared__ double Bpart[8];
    __shared__ double invdiag[8];
    __shared__ double solveV[8];
    __shared__ double ageo_s[8];
    __shared__ double h2s[16];
    __shared__ double d2z_s[8];
    __shared__ double h3s[8];

    // Preload metric-net weights as f64 (reused 17x). 256 lanes: <=3 each.
    for (int i = tid; i < 128; i += 256) w_me1[i] = (double)me_w1[i];
    for (int i = tid; i < 16;  i += 256) b_me1[i] = (double)me_b1[i];
    for (int i = tid; i < 576; i += 256) {
        int m = i >> 4, j = i & 15;
        w_me2[m * W2PAD + j] = (double)me_w2[i];
    }
    for (int i = tid; i < 36;  i += 256) b_me2[i] = (double)me_b2[i];

    // Phase 1a: h = v * se_in_w + se_in_b at the 4 trailing steps (64 lanes).
    if (tid < 64) {
        int t = tid >> 4, c = tid & 15;
        double v = (double)values[(size_t)b * Ln + (Ln - 4 + t)];
        h16[t][c] = (double)se_in_w[c] * v + (double)se_in_b[c];
    }
    __syncthreads();

    // Phase 1b: causal conv (k=3, left-pad 2) + silu at t = L-2, L-1 (16 lanes).
    if (tid < 16) {
        int t = tid >> 3, d = tid & 7;
        double s = (double)se_conv_b[d];
        for (int k = 0; k < 3; ++k)
            for (int c = 0; c < 16; ++c)
                s += (double)se_conv_w[d * 48 + c * 3 + k] * h16[t + k][c];
        sh[t][d] = silu_d(s);
    }
    __syncthreads();

    // Phase 1c: out-projection -> z (16 lanes).
    if (tid < 16) {
        int t = tid >> 3, d = tid & 7;
        double s = (double)se_out_b[d];
        for (int c = 0; c < 8; ++c) s += (double)se_out_w[d * 8 + c] * sh[t][c];
        zl[t][d] = s;
    }
    __syncthreads();

    // Phase 2a: build the 17 eval points (e=0 base; 1..8 +eps; 9..16 -eps). 136 tasks.
    if (tid < 136) {
        int e = tid >> 3, i = tid & 7;
        double v = zl[1][i];
        if (e >= 1 && e <= 8)  { if (i == e - 1) v += EPSd; }
        else if (e >= 9)       { if (i == e - 9) v -= EPSd; }
        zs[e][i] = v;
    }
    __syncthreads();

    // Phase 2b: h1 = silu(me_w1 zz + b1): 272 dot-8s over 256 lanes.
    for (int idx = tid; idx < 272; idx += 256) {
        int e = idx >> 4, j = idx & 15;
        double s = b_me1[j];
        const double* w = &w_me1[j * 8];
        const double* z = &zs[e][0];
        for (int i = 0; i < 8; ++i) s += w[i] * z[i];
        h1s[e][j] = silu_d(s);
    }
    __syncthreads();

    // Phase 2c: Lr = me_w2 h1 + b2 (+softplus on diag): 612 dot-16s over 256 lanes.
    for (int idx = tid; idx < 612; idx += 256) {
        int e = idx / 36, m = idx - e * 36;
        double s = b_me2[m];
        const double* w = &w_me2[m * W2PAD];
        const double* h = &h1s[e][0];
        for (int j = 0; j < 16; ++j) s += w[j] * h[j];
        if ((DIAG_MASK >> m) & 1ull) s = softplus_d(s) + DIAG_MIN;
        Lrs[e][m] = s;
    }
    __syncthreads();

    // Phase 2d: g = L L^T for e = 1..16: 576 short dots over 256 lanes.
    for (int idx = tid; idx < 576; idx += 256) {
        int e = 1 + idx / 36, m = idx - (e - 1) * 36;
        int i = ROW36[m], j = COL36[m];
        const double* Li = &Lrs[e][i * (i + 1) / 2];
        const double* Lj = &Lrs[e][j * (j + 1) / 2];
        double s = 0.0;
        for (int k = 0; k <= j; ++k) s += Li[k] * Lj[k];
        gs[e][m] = s;
    }
    __syncthreads();

    // Phase 3: FD contraction (lanes 0..7, static-index accumulation -> no
    // scratch; rule #20) + diag reciprocals (lanes 8..15).
    if (tid >= 8 && tid < 16) {
        int i = tid - 8;
        invdiag[i] = 1.0 / Lrs[0][i * (i + 1) / 2 + i];
    }
    if (tid < 8) {
        const int r = tid;
        double dz[8];
        #pragma unroll
        for (int i = 0; i < 8; ++i) dz[i] = zl[1][i] - zl[0][i];
        double w[8];
        #pragma unroll
        for (int l = 0; l < 8; ++l) w[l] = 0.0;
        const double inv2e = 1.0 / (2.0 * EPSd);
        #pragma unroll
        for (int m = 0; m < 36; ++m) {
            const int i = ROW36[m], j = COL36[m];  // folds to immediates (unrolled)
            double d = (gs[1 + r][m] - gs[9 + r][m]) * inv2e;
            w[j] += d * dz[i];
            if (i != j) w[i] += d * dz[j];
        }
        double Br = 0.0;
        #pragma unroll
        for (int l = 0; l < 8; ++l) {
            Apart[r][l] = dz[r] * w[l];
            Br += w[l] * dz[l];
        }
        Bpart[r] = Br;
    }
    __syncthreads();

    // Phase 4a: v[l] = 2*sum_r A[r][l] - B[l]  (8 lanes).
    if (tid < 8) {
        double a = 0.0;
        #pragma unroll
        for (int r = 0; r < 8; ++r) a += Apart[r][tid];
        solveV[tid] = 2.0 * a - Bpart[tid];
    }
    __syncthreads();

    // Phase 4b: solve g x = v via Cholesky factor (lane 0, fully unrolled ->
    // registers, invdiag multiplies instead of divides).
    if (tid == 0) {
        double y[8];
        #pragma unroll
        for (int i = 0; i < 8; ++i) {
            double s = solveV[i];
            #pragma unroll
            for (int j = 0; j < 8; ++j) if (j < i) s -= Lrs[0][i * (i + 1) / 2 + j] * y[j];
            y[i] = s * invdiag[i];
        }
        double x[8];
        #pragma unroll
        for (int i = 7; i >= 0; --i) {
            double s = y[i];
            #pragma unroll
            for (int j = 0; j < 8; ++j) if (j > i) s -= Lrs[0][j * (j + 1) / 2 + i] * x[j];
            x[i] = s * invdiag[i];
            ageo_s[i] = -0.5 * x[i];
        }
    }
    __syncthreads();

    // Phase 4c: ef head layer 1 (16 lanes): h2 = tanh(ef_w1 [z,dz] + b1).
    if (tid < 16) {
        double s = (double)ef_b1[tid];
        const float* w = &ef_w1[tid * 16];
        for (int i = 0; i < 8; ++i)  s += (double)w[i] * zl[1][i];
        for (int i = 0; i < 8; ++i)  s += (double)w[8 + i] * (zl[1][i] - zl[0][i]);
        h2s[tid] = tanh(s);
    }
    __syncthreads();

    // Phase 4d: d2z = a_geo + ef_scale * (ef_w2 h2 + b2)  (8 lanes).
    if (tid < 8) {
        double s = (double)ef_b2[tid];
        const float* w = &ef_w2[tid * 16];
        for (int j = 0; j < 16; ++j) s += (double)w[j] * h2s[j];
        d2z_s[tid] = ageo_s[tid] + s * (double)ef_scale[0];
    }
    __syncthreads();

    // Phase 4e: mu head layer 1 (8 lanes): h3 = silu(mu_w1 d2z + b1).
    if (tid < 8) {
        double s = (double)mu_b1[tid];
        const float* w = &mu_w1[tid * 8];
        for (int i = 0; i < 8; ++i) s += (double)w[i] * d2z_s[i];
        h3s[tid] = silu_d(s);
    }
    __syncthreads();

    // Phase 4f: final dot + output (lane 0).
    if (tid == 0) {
        double mu = (double)mu_b2[0];
        for (int j = 0; j < 8; ++j) mu += (double)mu_w2[j] * h3s[j];
        double vL1 = (double)values[(size_t)b * Ln + (Ln - 1)];
        double vL2 = (double)values[(size_t)b * Ln + (Ln - 2)];
        out[b] = (float)(vL1 + (vL1 - vL2) + mu);
    }
}

extern "C" void kernel_launch(void* const* d_in, const int* in_sizes, int n_in,
                              void* d_out, int out_size, void* d_ws, size_t ws_size,
                              hipStream_t stream) {
    (void)in_sizes; (void)n_in; (void)out_size; (void)d_ws; (void)ws_size;
    const float* values    = (const float*)d_in[0];
    const float* se_in_w   = (const float*)d_in[1];
    const float* se_in_b   = (const float*)d_in[2];
    const float* se_conv_w = (const float*)d_in[3];
    const float* se_conv_b = (const float*)d_in[4];
    const float* se_out_w  = (const float*)d_in[5];
    const float* se_out_b  = (const float*)d_in[6];
    const float* me_w1     = (const float*)d_in[7];
    const float* me_b1     = (const float*)d_in[8];
    const float* me_w2     = (const float*)d_in[9];
    const float* me_b2     = (const float*)d_in[10];
    const float* ef_w1     = (const float*)d_in[11];
    const float* ef_b1     = (const float*)d_in[12];
    const float* ef_w2     = (const float*)d_in[13];
    const float* ef_b2     = (const float*)d_in[14];
    const float* ef_scale  = (const float*)d_in[15];
    const float* mu_w1     = (const float*)d_in[16];
    const float* mu_b1     = (const float*)d_in[17];
    const float* mu_w2     = (const float*)d_in[18];
    const float* mu_b2     = (const float*)d_in[19];
    float* out = (float*)d_out;

    hipLaunchKernelGGL(memodel_kernel, dim3(Bn), dim3(256), 0, stream,
                       values, se_in_w, se_in_b, se_conv_w, se_conv_b,
                       se_out_w, se_out_b, me_w1, me_b1, me_w2, me_b2,
                       ef_w1, ef_b1, ef_w2, ef_b2, ef_scale,
                       mu_w1, mu_b1, mu_w2, mu_b2, out);
}